// Round 2
// baseline (621.836 us; speedup 1.0000x reference)
//
#include <hip/hip_runtime.h>
#include <math.h>

// Problem constants
#define N_TOK 1024
#define TOPK  2
#define NEXP  16
#define HID   1024   // H
#define DIM   2048   // D
#define RANK  16
#define NPAIR (N_TOK * TOPK)
#define MOE_SCALE 0.25f
#define MAXTILES 31  // sum_e ceil(cnt_e/128) <= 15 + 16

typedef __attribute__((ext_vector_type(8))) short short8;
typedef __attribute__((ext_vector_type(4))) float floatx4;

static __device__ __forceinline__ unsigned short f2bf(float f) {
    union { float f; unsigned int u; } v; v.f = f;
    unsigned int u = v.u;
    u += 0x7fffu + ((u >> 16) & 1u);   // RNE
    return (unsigned short)(u >> 16);
}

static __device__ __forceinline__ short8 cvt8(float4 a, float4 b) {
    short8 o;
    o[0] = (short)f2bf(a.x); o[1] = (short)f2bf(a.y);
    o[2] = (short)f2bf(a.z); o[3] = (short)f2bf(a.w);
    o[4] = (short)f2bf(b.x); o[5] = (short)f2bf(b.y);
    o[6] = (short)f2bf(b.z); o[7] = (short)f2bf(b.w);
    return o;
}

// Consumer-side bf16 fragment fetch from fp32 LDS tile (256-B rows, XOR-16
// chunk swizzle matched by the glds source pre-swizzle below).
static __device__ __forceinline__ short8 ldcvt(const float* base, int r, int c) {
    float4 f0 = *(const float4*)(base + r * 64 + (((c)     ^ (r & 15)) * 4));
    float4 f1 = *(const float4*)(base + r * 64 + (((c + 1) ^ (r & 15)) * 4));
    return cvt8(f0, f1);
}

#define BAR() do { asm volatile("s_waitcnt lgkmcnt(0)" ::: "memory"); \
                   __builtin_amdgcn_s_barrier(); \
                   asm volatile("" ::: "memory"); } while (0)

// global -> LDS direct (16 B / lane). LDS arg is wave-uniform; global arg is
// per-lane (pre-swizzled source = both-sides swizzle, rule #21).
#define GLDS16(G, L) __builtin_amdgcn_global_load_lds( \
    (const __attribute__((address_space(1))) void*)(G), \
    (__attribute__((address_space(3))) void*)(L), 16, 0, 0)

// ---------------------------------------------------------------------------
// Routing: sort pair indices by expert + dense (e,mt) worklist.
// ---------------------------------------------------------------------------
__global__ void k_routing(const int* __restrict__ ids,
                          int* __restrict__ offs,      // [NEXP+1]
                          int* __restrict__ sorted,    // [NPAIR]
                          int* __restrict__ tlist,     // [MAXTILES] (e<<8|mt)
                          int* __restrict__ tcount) {
    __shared__ int s_cnt[NEXP];
    __shared__ int s_off[NEXP + 1];
    int tid = threadIdx.x;
    if (tid < NEXP) s_cnt[tid] = 0;
    __syncthreads();
    for (int p = tid; p < NPAIR; p += blockDim.x) atomicAdd(&s_cnt[ids[p]], 1);
    __syncthreads();
    if (tid == 0) {
        int acc = 0;
        for (int e = 0; e < NEXP; ++e) { s_off[e] = acc; acc += s_cnt[e]; }
        s_off[NEXP] = acc;
        int t = 0;
        for (int e = 0; e < NEXP; ++e) {
            int c = s_off[e + 1] - s_off[e];
            for (int m = 0; m * 128 < c; ++m) tlist[t++] = (e << 8) | m;
        }
        *tcount = t;
    }
    __syncthreads();
    if (tid <= NEXP) offs[tid] = s_off[tid];
    if (tid < NEXP) s_cnt[tid] = s_off[tid];
    __syncthreads();
    for (int p = tid; p < NPAIR; p += blockDim.x) {
        int e = ids[p];
        int slot = atomicAdd(&s_cnt[e], 1);
        sorted[slot] = p;
    }
}

// ---------------------------------------------------------------------------
// x (fp32) -> bf16 once (A side of k_up).
// ---------------------------------------------------------------------------
__global__ void k_cvt_x(const float* __restrict__ x, unsigned short* __restrict__ xbf) {
    size_t i = (size_t)blockIdx.x * blockDim.x + threadIdx.x;   // 8 elems/thread
    const float4* p = (const float4*)(x + i * 8);
    float4 a = p[0], b = p[1];
    *(short8*)(xbf + i * 8) = cvt8(a, b);
}

// ---------------------------------------------------------------------------
// Shared GEMM machinery. Both GEMMs: 128 tokens x 64 output cols, BK=64.
// All staging via global_load_lds: zero staging VGPRs, counted vmcnt(9)
// (9 glds/wave/chunk: 4 A + 4 B + 1 U) -> loads stay in flight across raw
// s_barrier. LDS double-buffered: sA bf16 [2][128][64], sB f32 [2][64][64],
// sU f32 [2][16][64]  => 72 KB => 2 blocks/CU.
// ---------------------------------------------------------------------------
#define G_ISSUE(BUF) do {                                                    \
    _Pragma("unroll") for (int i = 0; i < 4; ++i) {                          \
        GLDS16(aq[i], &sA[BUF][(wv * 32 + 8 * i) * 64]); aq[i] += 64; }      \
    _Pragma("unroll") for (int i = 0; i < 4; ++i) {                          \
        GLDS16(bq[i], &sB[BUF][(wv * 16 + 4 * i) * 64]); bq[i] += 64; }      \
    GLDS16(uq, &sU[BUF][(wv * 4) * 64]); uq += 64;                           \
} while (0)

#define G_MSTEP(BUF) do {                                                    \
    _Pragma("unroll") for (int kk = 0; kk < 2; ++kk) {                       \
        int r0 = wv * 32 + lm, r1 = r0 + 16;                                 \
        short8 af0 = *(const short8*)(&sA[BUF][r0 * 64 + (((kk * 4 + lq) ^ (r0 & 7)) * 8)]); \
        short8 af1 = *(const short8*)(&sA[BUF][r1 * 64 + (((kk * 4 + lq) ^ (r1 & 7)) * 8)]); \
        int c = kk * 8 + lq * 2;                                             \
        short8 uf = ldcvt(&sU[BUF][0], lm, c);                               \
        acct[0] = __builtin_amdgcn_mfma_f32_16x16x32_bf16(af0, uf, acct[0], 0, 0, 0); \
        acct[1] = __builtin_amdgcn_mfma_f32_16x16x32_bf16(af1, uf, acct[1], 0, 0, 0); \
        _Pragma("unroll") for (int n2 = 0; n2 < 4; ++n2) {                   \
            short8 bf = ldcvt(&sB[BUF][0], n2 * 16 + lm, c);                 \
            acc[0][n2] = __builtin_amdgcn_mfma_f32_16x16x32_bf16(af0, bf, acc[0][n2], 0, 0, 0); \
            acc[1][n2] = __builtin_amdgcn_mfma_f32_16x16x32_bf16(af1, bf, acc[1][n2], 0, 0, 0); \
        }                                                                    \
    }                                                                        \
} while (0)

// Counted-vmcnt double-buffer pipeline: never drain vmcnt to 0 mid-loop.
#define G_PIPE(NC)                                                           \
    G_ISSUE(0); G_ISSUE(1);                                                  \
    _Pragma("unroll 1")                                                      \
    for (int t = 0; t < (NC); ++t) {                                         \
        if (t < (NC) - 1) asm volatile("s_waitcnt vmcnt(9)" ::: "memory");   \
        else              asm volatile("s_waitcnt vmcnt(0)" ::: "memory");   \
        __builtin_amdgcn_s_barrier();                                        \
        asm volatile("" ::: "memory");                                       \
        G_MSTEP(t & 1);                                                      \
        asm volatile("s_waitcnt lgkmcnt(0)" ::: "memory");                   \
        __builtin_amdgcn_s_barrier();                                        \
        asm volatile("" ::: "memory");                                       \
        if (t < (NC) - 2) G_ISSUE(t & 1);                                    \
    }

// ---------------------------------------------------------------------------
// Up-GEMM: 128 tokens x (32 gate + 32 mul) cols, NC=32. Fused LoRA-A dot
// (acct) + rank-16 LoRA-B + erf-gelu*mul epilogue -> act[slot][h] bf16.
// ---------------------------------------------------------------------------
__global__ __launch_bounds__(256, 2) void k_up(
        const unsigned short* __restrict__ xbf, const float* __restrict__ w_up,
        const float* __restrict__ up_a, const float* __restrict__ up_b,
        const int* __restrict__ offs, const int* __restrict__ sorted,
        const int* __restrict__ tlist, const int* __restrict__ tcount,
        unsigned short* __restrict__ act) {
    int wt = blockIdx.x;
    if (wt >= *tcount) return;
    int code = tlist[wt];
    int e = code >> 8, mt = code & 255;
    int nt = blockIdx.y;                  // 0..31 : cols nt*32 (gate) pair
    int off = offs[e], cnt = offs[e + 1] - off;

    __shared__ __align__(16) unsigned short sA[2][128 * 64];   // 32 KB
    __shared__ __align__(16) float          sB[2][64 * 64];    // 32 KB
    __shared__ __align__(16) float          sU[2][16 * 64];    //  8 KB

    int tid = threadIdx.x, lane = tid & 63, wv = tid >> 6;
    int lm = lane & 15, lq = lane >> 4;
    int l3 = lane >> 3, l7 = lane & 7, l4 = lane >> 4, l15 = lane & 15;

    // glds source pointers (pre-swizzled columns)
    int acol = ((l7 ^ l3) * 8);                         // bf16 elems
    const unsigned short* aq[4];
#pragma unroll
    for (int i = 0; i < 4; ++i) {
        int r = wv * 32 + 8 * i + l3;                   // LDS tile row 0..127
        int g = mt * 128 + r; if (g >= cnt) g = cnt - 1;
        int p = sorted[off + g];
        aq[i] = xbf + (size_t)(p >> 1) * DIM + acol;
    }
    const float* bq[4];
#pragma unroll
    for (int i = 0; i < 4; ++i) {
        int tr = wv * 16 + 4 * i + l4;                  // 0..63
        int wrow = (tr < 32) ? (nt * 32 + tr) : (HID + nt * 32 + (tr - 32));
        int bcol = ((l15 ^ (tr & 15)) * 4);             // f32 elems
        bq[i] = w_up + ((size_t)e * 2 * HID + wrow) * DIM + bcol;
    }
    int ur = wv * 4 + l4;                               // 0..15
    const float* uq = up_a + ((size_t)e * RANK + ur) * DIM + ((l15 ^ ur) * 4);

    floatx4 zero = {0.f, 0.f, 0.f, 0.f};
    floatx4 acc[2][4], acct[2];
#pragma unroll
    for (int i = 0; i < 2; ++i) {
        acct[i] = zero;
#pragma unroll
        for (int j = 0; j < 4; ++j) acc[i][j] = zero;
    }

    G_PIPE(32);

    // spill t (lora-A dots) to LDS; sA dead after final barrier
    float* t_s = (float*)&sA[0][0];   // [128][16] fp32 = 8 KB
#pragma unroll
    for (int i = 0; i < 2; ++i)
#pragma unroll
        for (int j = 0; j < 4; ++j)
            t_s[(wv * 32 + i * 16 + lq * 4 + j) * 16 + lm] = MOE_SCALE * acct[i][j];
    BAR();

    // epilogue: LoRA rank-16 + erf-gelu * mul -> act[slot][h] (bf16)
    const float* upb = up_b + (size_t)e * 2 * HID * RANK;
#pragma unroll
    for (int n2 = 0; n2 < 2; ++n2) {
        int h = nt * 32 + n2 * 16 + lm;
        const float* b1 = upb + (size_t)h * RANK;
        const float* b2 = upb + (size_t)(h + HID) * RANK;
        float r1[RANK], r2[RANK];
#pragma unroll
        for (int i = 0; i < RANK; ++i) { r1[i] = b1[i]; r2[i] = b2[i]; }
#pragma unroll
        for (int i = 0; i < 2; ++i) {
#pragma unroll
            for (int r = 0; r < 4; ++r) {
                int rl = wv * 32 + i * 16 + lq * 4 + r;
                int gg = mt * 128 + rl;
                if (gg < cnt) {
                    int slot = off + gg;
                    const float* tv = t_s + rl * 16;
                    float s1 = acc[i][n2][r], s2 = acc[i][n2 + 2][r];
#pragma unroll
                    for (int j = 0; j < RANK; ++j) { s1 += tv[j] * r1[j]; s2 += tv[j] * r2[j]; }
                    float gl = 0.5f * s1 * (1.f + erff(s1 * 0.70710678118654752f));
                    act[(size_t)slot * HID + h] = f2bf(gl * s2);
                }
            }
        }
    }
}

// ---------------------------------------------------------------------------
// Down-GEMM: 128 tokens x 64 d-rows, NC=16. Fused t2 (acct) + LoRA-B +
// topk-weight + atomic scatter-add epilogue.
// ---------------------------------------------------------------------------
__global__ __launch_bounds__(256, 2) void k_down(
        const unsigned short* __restrict__ actg, const float* __restrict__ w_down,
        const float* __restrict__ tw, const float* __restrict__ down_a,
        const float* __restrict__ down_b,
        const int* __restrict__ offs, const int* __restrict__ sorted,
        const int* __restrict__ tlist, const int* __restrict__ tcount,
        float* __restrict__ out) {
    int wt = blockIdx.x;
    if (wt >= *tcount) return;
    int code = tlist[wt];
    int e = code >> 8, mt = code & 255;
    int nt = blockIdx.y;                  // 0..31 : d-rows nt*64
    int off = offs[e], cnt = offs[e + 1] - off;

    __shared__ __align__(16) unsigned short sA[2][128 * 64];
    __shared__ __align__(16) float          sB[2][64 * 64];
    __shared__ __align__(16) float          sU[2][16 * 64];

    int tid = threadIdx.x, lane = tid & 63, wv = tid >> 6;
    int lm = lane & 15, lq = lane >> 4;
    int l3 = lane >> 3, l7 = lane & 7, l4 = lane >> 4, l15 = lane & 15;

    int acol = ((l7 ^ l3) * 8);
    const unsigned short* aq[4];
#pragma unroll
    for (int i = 0; i < 4; ++i) {
        int r = wv * 32 + 8 * i + l3;
        int g = mt * 128 + r; if (g >= cnt) g = cnt - 1;
        aq[i] = actg + (size_t)(off + g) * HID + acol;
    }
    const float* bq[4];
#pragma unroll
    for (int i = 0; i < 4; ++i) {
        int tr = wv * 16 + 4 * i + l4;                  // 0..63
        int bcol = ((l15 ^ (tr & 15)) * 4);
        bq[i] = w_down + ((size_t)e * DIM + nt * 64 + tr) * HID + bcol;
    }
    int ur = wv * 4 + l4;
    const float* uq = down_a + ((size_t)e * RANK + ur) * HID + ((l15 ^ ur) * 4);

    floatx4 zero = {0.f, 0.f, 0.f, 0.f};
    floatx4 acc[2][4], acct[2];
#pragma unroll
    for (int i = 0; i < 2; ++i) {
        acct[i] = zero;
#pragma unroll
        for (int j = 0; j < 4; ++j) acc[i][j] = zero;
    }

    G_PIPE(16);

    float* t_s = (float*)&sA[0][0];
#pragma unroll
    for (int i = 0; i < 2; ++i)
#pragma unroll
        for (int j = 0; j < 4; ++j)
            t_s[(wv * 32 + i * 16 + lq * 4 + j) * 16 + lm] = MOE_SCALE * acct[i][j];
    BAR();

#pragma unroll
    for (int n2 = 0; n2 < 4; ++n2) {
        int dd = nt * 64 + n2 * 16 + lm;
        const float* rb = down_b + ((size_t)e * DIM + dd) * RANK;
        float rbv[RANK];
#pragma unroll
        for (int i2 = 0; i2 < RANK; ++i2) rbv[i2] = rb[i2];
#pragma unroll
        for (int i = 0; i < 2; ++i) {
#pragma unroll
            for (int r = 0; r < 4; ++r) {
                int rl = wv * 32 + i * 16 + lq * 4 + r;
                int gg = mt * 128 + rl;
                if (gg < cnt) {
                    int slot = off + gg;
                    int pp = sorted[slot];
                    const float* tv = t_s + rl * 16;
                    float val = acc[i][n2][r];
#pragma unroll
                    for (int j = 0; j < RANK; ++j) val += tv[j] * rbv[j];
                    atomicAdd(&out[(size_t)(pp >> 1) * DIM + dd], val * tw[pp]);
                }
            }
        }
    }
}

// ---------------------------------------------------------------------------
extern "C" void kernel_launch(void* const* d_in, const int* in_sizes, int n_in,
                              void* d_out, int out_size, void* d_ws, size_t ws_size,
                              hipStream_t stream) {
    const float* x      = (const float*)d_in[0];
    const float* tw     = (const float*)d_in[1];
    const int*   ids    = (const int*)d_in[2];
    const float* w_up   = (const float*)d_in[3];
    const float* w_down = (const float*)d_in[4];
    const float* up_a   = (const float*)d_in[5];
    const float* up_b   = (const float*)d_in[6];
    const float* down_a = (const float*)d_in[7];
    const float* down_b = (const float*)d_in[8];
    float* out = (float*)d_out;

    char* ws = (char*)d_ws;
    int* offs   = (int*)ws;                                  // 68 B
    int* tlist  = (int*)(ws + 1024);                         // 124 B
    int* tcount = (int*)(ws + 2048);                         // 4 B
    int* sorted = (int*)(ws + 4096);                         // 8 KB
    unsigned short* act = (unsigned short*)(ws + 65536);     // 4 MB (NPAIR*HID bf16)
    unsigned short* xbf = (unsigned short*)(ws + 65536 + (size_t)NPAIR * HID * 2); // 4 MB

    hipMemsetAsync(d_out, 0, (size_t)out_size * sizeof(float), stream);

    k_routing<<<1, 256, 0, stream>>>(ids, offs, sorted, tlist, tcount);
    k_cvt_x<<<(N_TOK * DIM / 8 / 256), 256, 0, stream>>>(x, xbf);

    dim3 gup(MAXTILES, 32);
    k_up<<<gup, 256, 0, stream>>>(xbf, w_up, up_a, up_b, offs, sorted, tlist, tcount, act);

    dim3 gdn(MAXTILES, 32);
    k_down<<<gdn, 256, 0, stream>>>(act, w_down, tw, down_a, down_b, offs, sorted, tlist, tcount, out);
}